// Round 17
// baseline (71.775 us; speedup 1.0000x reference)
//
#include <hip/hip_runtime.h>

typedef short bf8 __attribute__((ext_vector_type(8)));   // 8 bf16 bit patterns (guide §3)
typedef float f32x4 __attribute__((ext_vector_type(4)));
typedef unsigned short ushort;
typedef unsigned int uint;

#define MFMA16(a, b, c) __builtin_amdgcn_mfma_f32_16x16x32_bf16((a), (b), (c), 0, 0, 0)

// fp32 -> bf16 bits, RNE
static __device__ __forceinline__ ushort f2bf(float f) {
    union { float f; uint u; } v; v.f = f;
    uint u = v.u + 0x7FFFu + ((v.u >> 16) & 1u);
    return (ushort)(u >> 16);
}
static __device__ __forceinline__ float bf2f(ushort u) {
    union { uint u; float f; } v; v.u = ((uint)u) << 16; return v.f;
}
static __device__ __forceinline__ uint pk2(float a, float b) {
    return (uint)f2bf(a) | ((uint)f2bf(b) << 16);
}
// async 16B global->LDS DMA (dest: wave-uniform base + lane*16, per-lane src)
static __device__ __forceinline__ void gload16(const void* g, void* l) {
    __builtin_amdgcn_global_load_lds((const __attribute__((address_space(1))) void*)g,
                                     (__attribute__((address_space(3))) void*)l, 16, 0, 0);
}

// ---------------------------------------------------------------------------
// Kernel 1: W fp32 [1024][128] -> bf16 W^T [3][128 n][1024 k]
// ---------------------------------------------------------------------------
__global__ __launch_bounds__(256) void k_wconvert(const float* __restrict__ Wq,
                                                  const float* __restrict__ Wk,
                                                  const float* __restrict__ Wv,
                                                  ushort* __restrict__ wT) {
    int idx  = blockIdx.x * 256 + threadIdx.x;   // [3][128 kc][128 n]
    int proj = idx >> 14;
    int kc   = (idx >> 7) & 127;                 // chunk of 8 k
    int n    = idx & 127;                        // fastest -> coalesced reads
    const float* W = (proj == 0) ? Wq : (proj == 1 ? Wk : Wv);
    uint4 w;
    float f[8];
#pragma unroll
    for (int j = 0; j < 8; ++j) f[j] = W[(kc * 8 + j) * 128 + n];
    w.x = pk2(f[0], f[1]); w.y = pk2(f[2], f[3]);
    w.z = pk2(f[4], f[5]); w.w = pk2(f[6], f[7]);
    *(uint4*)&wT[(size_t)proj * 131072 + (size_t)n * 1024 + kc * 8] = w;
}

// ---------------------------------------------------------------------------
// Kernel 2: fused QKV projection (ROUND-10 CONFIG — proven local optimum).
// BM=64, BN=128, BK=64, 768 blocks = 3/CU, single-buffer, no cross-barrier
// register state. B via global_load_lds w=16 (pre-swizzled src, linear dest);
// A global->reg->cvt->ds_write. LDS 24 KB.
// ---------------------------------------------------------------------------
__global__ __launch_bounds__(256, 3) void k_proj(const float* __restrict__ x,
                                                 const ushort* __restrict__ wT,
                                                 ushort* __restrict__ qb,
                                                 ushort* __restrict__ kb,
                                                 ushort* __restrict__ vT) {
    const int bx = blockIdx.x;
    const int mt = bx & 255;          // 256 m-tiles of 64 rows (same-x blocks 256 apart -> same XCD)
    const int proj = bx >> 8;         // 0,1,2
    const int tid = threadIdx.x, lane = tid & 63, wid = tid >> 6;
    const int wm = wid >> 1, wn = wid & 1;
    const int m0 = mt * 64;

    __shared__ __align__(16) ushort sm[64 * 64 + 128 * 64];  // lA 8KB + lB 16KB
    ushort* lA = sm;               // [64 m][64 k] swizzled
    ushort* lB = sm + 64 * 64;     // [128 n][64 k] swizzled (data), linear dest for DMA

    const ushort* wTp = wT + (size_t)proj * 131072;
    f32x4 acc[2][4] = {};

    const int arow = tid >> 2, aq = tid & 3;   // A: row, 16-col group
    const float* xrow = x + (size_t)(m0 + arow) * 1024 + aq * 16;

    for (int kt = 0; kt < 1024; kt += 64) {
        __syncthreads();   // previous MFMA reads done
#pragma unroll
        for (int c = 0; c < 4; ++c) {
            int chunk = tid + 256 * c;
            int n = chunk >> 3, ir = (chunk & 7) * 8;
            gload16(wTp + (size_t)n * 1024 + kt + (ir ^ ((n & 7) << 3)),
                    lB + (size_t)(wid * 64 + 256 * c) * 8);
        }
        {
            const float* xs = xrow + kt;
            float4 a0 = *(const float4*)(xs);
            float4 a1 = *(const float4*)(xs + 4);
            float4 a2 = *(const float4*)(xs + 8);
            float4 a3 = *(const float4*)(xs + 12);
            uint4 w0, w1;
            w0.x = pk2(a0.x, a0.y); w0.y = pk2(a0.z, a0.w);
            w0.z = pk2(a1.x, a1.y); w0.w = pk2(a1.z, a1.w);
            w1.x = pk2(a2.x, a2.y); w1.y = pk2(a2.z, a2.w);
            w1.z = pk2(a3.x, a3.y); w1.w = pk2(a3.z, a3.w);
            const int swz = (arow & 7) << 3;
            const int ir0 = aq * 16;
            *(uint4*)&lA[arow * 64 + (ir0 ^ swz)] = w0;
            *(uint4*)&lA[arow * 64 + ((ir0 + 8) ^ swz)] = w1;
        }
        __syncthreads();   // drains vmcnt (DMA) + lgkmcnt (ds_write)

#pragma unroll
        for (int kk = 0; kk < 2; ++kk) {
            const int ir = kk * 32 + (lane >> 4) * 8;
            bf8 a[2], bv[4];
#pragma unroll
            for (int mf = 0; mf < 2; ++mf) {
                int r = wm * 32 + mf * 16 + (lane & 15);
                a[mf] = *(const bf8*)&lA[r * 64 + (ir ^ ((r & 7) << 3))];
            }
#pragma unroll
            for (int nf = 0; nf < 4; ++nf) {
                int r = wn * 64 + nf * 16 + (lane & 15);
                bv[nf] = *(const bf8*)&lB[r * 64 + (ir ^ ((r & 7) << 3))];
            }
#pragma unroll
            for (int mf = 0; mf < 2; ++mf)
#pragma unroll
                for (int nf = 0; nf < 4; ++nf)
                    acc[mf][nf] = MFMA16(a[mf], bv[nf], acc[mf][nf]);
        }
    }
    __syncthreads();   // all MFMA reads done before epilogue reuses sm

    // epilogue via LDS restage for coalesced b128 stores.
    // C/D layout (m89): col = lane&15, row = (lane>>4)*4 + i
    if (proj < 2) {
        ushort* lT = sm;  // [64 row][136]
#pragma unroll
        for (int mf = 0; mf < 2; ++mf) {
            int row = wm * 32 + mf * 16 + ((lane >> 4) << 2);
#pragma unroll
            for (int nf = 0; nf < 4; ++nf) {
                int col = wn * 64 + nf * 16 + (lane & 15);
#pragma unroll
                for (int i = 0; i < 4; ++i)
                    lT[(row + i) * 136 + col] = f2bf(acc[mf][nf][i]);
            }
        }
        __syncthreads();
        const int row = tid >> 2, seg = (tid & 3) * 32;
        ushort* dst = (proj == 0 ? qb : kb) + (size_t)(m0 + row) * 128 + seg;
        const ushort* srcr = lT + row * 136 + seg;
#pragma unroll
        for (int j = 0; j < 4; ++j)
            *(uint4*)&dst[j * 8] = *(const uint4*)&srcr[j * 8];
    } else {
        ushort* lT = sm;  // [128 h][72]
#pragma unroll
        for (int mf = 0; mf < 2; ++mf) {
            int srow = wm * 32 + mf * 16 + ((lane >> 4) << 2);
#pragma unroll
            for (int nf = 0; nf < 4; ++nf) {
                int h = wn * 64 + nf * 16 + (lane & 15);
#pragma unroll
                for (int i = 0; i < 4; ++i)
                    lT[h * 72 + srow + i] = f2bf(acc[mf][nf][i]);
            }
        }
        __syncthreads();
        const int b = m0 >> 11, s0 = m0 & 2047;
        const int h = tid >> 1, so = (tid & 1) * 32;
        ushort* dst = vT + (size_t)b * 262144 + (size_t)h * 2048 + s0 + so;
#pragma unroll
        for (int j = 0; j < 4; ++j)
            *(uint4*)&dst[j * 8] = *(const uint4*)&lT[h * 72 + so + j * 8];
    }
}

// ---------------------------------------------------------------------------
// Kernel 3a: split-K causal attention, pass 1 — 2-PHASE PIPELINE (T3-min):
// K/V double-buffered (72 KB LDS, 2 blocks/CU); stage(t+1) issued BEFORE
// compute(t); ONE __syncthreads per tile. The barrier's vmcnt drain is now
// residual-only (stage ops have the whole compute phase ~500-700 cy in
// flight). Conditional stage is DMA-only — no cross-barrier register state.
// Fixed-base softmax (m == 0); row-sums via MFMA vs all-ones B.
// Partials bf16. 1D grid 1152: b = id&7 (batch->XCD), cx = 143-(id>>3).
// ---------------------------------------------------------------------------
#define NCHUNK 144

__global__ __launch_bounds__(256) void k_attn_part(const ushort* __restrict__ qb,
                                                   const ushort* __restrict__ kb,
                                                   const ushort* __restrict__ vT,
                                                   ushort* __restrict__ pacc,
                                                   float* __restrict__ pml) {
    const int id = blockIdx.x;
    const int b  = id & 7;
    const int cx = 143 - (id >> 3);      // 0..143, heavy chunks first
    int g = 0, base = 0;
#pragma unroll
    for (int gg = 0; gg < 8; ++gg) {
        int b0 = 2 * gg * (gg + 1);
        if (cx >= b0) { g = gg; base = b0; }
    }
    const int qt = 4 * g + (cx - base) / (g + 1);
    const int c  = (cx - base) % (g + 1);
    const int kt0 = 4 * c;
    const int kt1 = min(qt + 1, kt0 + 4);

    const int tid = threadIdx.x, lane = tid & 63, wid = tid >> 6;

    __shared__ __align__(16) ushort lK[2][64 * 128];  // [kpos][d]  swizzled, linear DMA dest
    __shared__ __align__(16) ushort lV[2][128 * 64];  // [h][kpos]  swizzled, linear DMA dest
    __shared__ __align__(16) ushort lP[4][16 * 64];   // per-wave [qrow][kpos] swizzled

    const ushort* kbase = kb + (size_t)b * 2048 * 128;
    const ushort* vbase = vT + (size_t)b * 262144;

    // stage K [64][128] + V [128][64]: 4+4 DMA/thread, pre-swizzled src
    auto stageKV = [&](int kt, int buf) {
        const ushort* kbt = kbase + (size_t)kt * 64 * 128;
#pragma unroll
        for (int cc = 0; cc < 4; ++cc) {
            int chunk = tid + 256 * cc;
            int rr = chunk >> 4, ir = (chunk & 15) * 8;
            gload16(kbt + (size_t)rr * 128 + (ir ^ ((rr & 7) << 3)),
                    &lK[buf][(size_t)(wid * 64 + 256 * cc) * 8]);
        }
        const ushort* vbt = vbase + kt * 64;
#pragma unroll
        for (int cc = 0; cc < 4; ++cc) {
            int chunk = tid + 256 * cc;
            int h = chunk >> 3, ir = (chunk & 7) * 8;
            gload16(vbt + (size_t)h * 2048 + (ir ^ ((h & 7) << 3)),
                    &lV[buf][(size_t)(wid * 64 + 256 * cc) * 8]);
        }
    };

    bf8 qf[4];
    {
        const ushort* qr = qb + (size_t)(b * 2048 + qt * 64 + wid * 16 + (lane & 15)) * 128;
#pragma unroll
        for (int kk = 0; kk < 4; ++kk)
            qf[kk] = *(const bf8*)&qr[kk * 32 + (lane >> 4) * 8];
    }
    bf8 onesf;
#pragma unroll
    for (int j = 0; j < 8; ++j) onesf[j] = (short)0x3F80;   // bf16 1.0

    f32x4 acc[8] = {};
    f32x4 accl = {};                                  // row sums of P
    const int r0 = wid * 16 + ((lane >> 4) << 2);     // local q row
    const int qg0 = qt * 64 + r0;

    // prologue: stage first tile
    stageKV(kt0, 0);
    __syncthreads();

    int cur = 0;
    for (int kt = kt0; kt < kt1; ++kt) {
        // issue next tile's DMA first — lands during compute below
        if (kt + 1 < kt1) stageKV(kt + 1, cur ^ 1);

        // QK^T : S[16 q][64 k]
        f32x4 sa[4] = {};
#pragma unroll
        for (int kk = 0; kk < 4; ++kk) {
            const int ir = kk * 32 + (lane >> 4) * 8;
#pragma unroll
            for (int nf = 0; nf < 4; ++nf) {
                int rr = nf * 16 + (lane & 15);
                bf8 kf = *(const bf8*)&lK[cur][rr * 128 + (ir ^ ((rr & 7) << 3))];
                sa[nf] = MFMA16(qf[kk], kf, sa[nf]);
            }
        }

        // P = exp(s/32), masked -> 0 (no max subtraction: |s| <= ~2)
        float p[4][4];
#pragma unroll
        for (int nf = 0; nf < 4; ++nf)
#pragma unroll
            for (int i = 0; i < 4; ++i) {
                float s = sa[nf][i] * 0.03125f;
                if (kt == qt) {
                    int kg = kt * 64 + nf * 16 + (lane & 15);
                    if (kg > qg0 + i) s = -1e30f;
                }
                p[nf][i] = __expf(s);
            }

        // P -> per-wave LDS tile (same-wave write->read)
#pragma unroll
        for (int nf = 0; nf < 4; ++nf)
#pragma unroll
            for (int i = 0; i < 4; ++i) {
                int rr = ((lane >> 4) << 2) + i, cp = nf * 16 + (lane & 15);
                lP[wid][rr * 64 + (cp ^ ((rr & 7) << 3))] = f2bf(p[nf][i]);
            }

        // PV: o[16 q][128 h] += P[16][64] . V[64][128]; l += P . ones
#pragma unroll
        for (int kk = 0; kk < 2; ++kk) {
            const int ir = kk * 32 + (lane >> 4) * 8;
            const int pr = lane & 15;
            bf8 pf = *(const bf8*)&lP[wid][pr * 64 + (ir ^ ((pr & 7) << 3))];
            accl = MFMA16(pf, onesf, accl);
#pragma unroll
            for (int nf = 0; nf < 8; ++nf) {
                int h = nf * 16 + (lane & 15);
                bf8 vf = *(const bf8*)&lV[cur][h * 64 + (ir ^ ((h & 7) << 3))];
                acc[nf] = MFMA16(pf, vf, acc[nf]);
            }
        }

        __syncthreads();   // drains residual vmcnt of stage(t+1); all waves done with buf[cur]
        cur ^= 1;
    }

    // epilogue: unnormalized partials (bf16) + row sums l (fp32)
    ushort* pa = pacc + ((size_t)(b * NCHUNK + cx) * 64) * 128;
#pragma unroll
    for (int nf = 0; nf < 8; ++nf) {
        int h = nf * 16 + (lane & 15);
#pragma unroll
        for (int i = 0; i < 4; ++i)
            pa[(size_t)(r0 + i) * 128 + h] = f2bf(acc[nf][i]);
    }
    if ((lane & 15) == 0) {
        float* pl = pml + (size_t)(b * NCHUNK + cx) * 64 + r0;
#pragma unroll
        for (int i = 0; i < 4; ++i) pl[i] = accl[i];
    }
}

// ---------------------------------------------------------------------------
// Kernel 3b: combine bf16 partials (unweighted: fixed softmax base).
// grid (8 b, 32 qt, 2 z): linear id = b + 8*qt + 256*z -> id%8 == b, the
// SAME XCD residue as k_attn_part's writers -> batch-b partials are read
// from the local XCD L2.  256 threads: row = t>>2, cols ((t&3)+4z)*16..+15
// ---------------------------------------------------------------------------
__global__ __launch_bounds__(256) void k_attn_comb(const ushort* __restrict__ pacc,
                                                   const float* __restrict__ pml,
                                                   float* __restrict__ out) {
    const int b = blockIdx.x, qt = blockIdx.y, z = blockIdx.z;
    const int tid = threadIdx.x;
    const int row = tid >> 2, cq = ((tid & 3) + 4 * z) * 16;
    const int g = qt >> 2;
    const int base = 2 * g * (g + 1) + (qt & 3) * (g + 1);
    const int nch = g + 1;   // ceil((qt+1)/4)

    float L = 0.f;
    for (int c = 0; c < nch; ++c)
        L += pml[(size_t)(b * NCHUNK + base + c) * 64 + row];
    const float inv = 1.0f / L;

    float s[16] = {};
    for (int c = 0; c < nch; ++c) {
        const ushort* pa = pacc + ((size_t)(b * NCHUNK + base + c) * 64 + row) * 128 + cq;
#pragma unroll
        for (int j = 0; j < 2; ++j) {
            uint4 t = *(const uint4*)&pa[j * 8];
            uint qw[4] = {t.x, t.y, t.z, t.w};
#pragma unroll
            for (int e = 0; e < 4; ++e) {
                s[j * 8 + 2 * e]     += bf2f((ushort)(qw[e] & 0xFFFFu));
                s[j * 8 + 2 * e + 1] += bf2f((ushort)(qw[e] >> 16));
            }
        }
    }
    float* o = out + ((size_t)(b * 2048 + qt * 64 + row)) * 128 + cq;
#pragma unroll
    for (int j = 0; j < 4; ++j) {
        f32x4 v;
#pragma unroll
        for (int e = 0; e < 4; ++e) v[e] = s[j * 4 + e] * inv;
        *(f32x4*)&o[j * 4] = v;
    }
}

// ---------------------------------------------------------------------------
extern "C" void kernel_launch(void* const* d_in, const int* in_sizes, int n_in,
                              void* d_out, int out_size, void* d_ws, size_t ws_size,
                              hipStream_t stream) {
    const float* x  = (const float*)d_in[0];
    const float* Wq = (const float*)d_in[1];
    const float* Wk = (const float*)d_in[2];
    const float* Wv = (const float*)d_in[3];
    float* out = (float*)d_out;

    char* ws = (char*)d_ws;
    ushort* qb = (ushort*)(ws);                       // bf16 [8*2048][128]  4 MB
    ushort* kb = (ushort*)(ws + (4u << 20));          // bf16 [8*2048][128]  4 MB
    ushort* vT = (ushort*)(ws + (8u << 20));          // bf16 [8][128][2048] 4 MB
    ushort* wT = (ushort*)(ws + (12u << 20));         // bf16 [3][128][1024] 768 KB
    float*  pml  = (float*)(ws + (13u << 20));        // [8][144][64] f32  0.3 MB
    ushort* pacc = (ushort*)(ws + (15u << 20));       // [8][144][64][128] bf16 18.9 MB

    k_wconvert<<<192, 256, 0, stream>>>(Wq, Wk, Wv, wT);
    k_proj<<<768, 256, 0, stream>>>(x, wT, qb, kb, vT);
    k_attn_part<<<NCHUNK * 8, 256, 0, stream>>>(qb, kb, vT, pacc, pml);
    k_attn_comb<<<dim3(8, 32, 2), 256, 0, stream>>>(pacc, pml, out);
}

// Round 18
// 67.651 us; speedup vs baseline: 1.0610x; 1.0610x over previous
//
#include <hip/hip_runtime.h>

typedef short bf8 __attribute__((ext_vector_type(8)));   // 8 bf16 bit patterns (guide §3)
typedef float f32x4 __attribute__((ext_vector_type(4)));
typedef unsigned short ushort;
typedef unsigned int uint;

#define MFMA16(a, b, c) __builtin_amdgcn_mfma_f32_16x16x32_bf16((a), (b), (c), 0, 0, 0)

// fp32 -> bf16 bits, RNE
static __device__ __forceinline__ ushort f2bf(float f) {
    union { float f; uint u; } v; v.f = f;
    uint u = v.u + 0x7FFFu + ((v.u >> 16) & 1u);
    return (ushort)(u >> 16);
}
static __device__ __forceinline__ float bf2f(ushort u) {
    union { uint u; float f; } v; v.u = ((uint)u) << 16; return v.f;
}
static __device__ __forceinline__ uint pk2(float a, float b) {
    return (uint)f2bf(a) | ((uint)f2bf(b) << 16);
}
// async 16B global->LDS DMA (dest: wave-uniform base + lane*16, per-lane src)
static __device__ __forceinline__ void gload16(const void* g, void* l) {
    __builtin_amdgcn_global_load_lds((const __attribute__((address_space(1))) void*)g,
                                     (__attribute__((address_space(3))) void*)l, 16, 0, 0);
}

// ---------------------------------------------------------------------------
// Kernel 1: W fp32 [1024][128] -> bf16 W^T [3][128 n][1024 k]
// ---------------------------------------------------------------------------
__global__ __launch_bounds__(256) void k_wconvert(const float* __restrict__ Wq,
                                                  const float* __restrict__ Wk,
                                                  const float* __restrict__ Wv,
                                                  ushort* __restrict__ wT) {
    int idx  = blockIdx.x * 256 + threadIdx.x;   // [3][128 kc][128 n]
    int proj = idx >> 14;
    int kc   = (idx >> 7) & 127;                 // chunk of 8 k
    int n    = idx & 127;                        // fastest -> coalesced reads
    const float* W = (proj == 0) ? Wq : (proj == 1 ? Wk : Wv);
    uint4 w;
    float f[8];
#pragma unroll
    for (int j = 0; j < 8; ++j) f[j] = W[(kc * 8 + j) * 128 + n];
    w.x = pk2(f[0], f[1]); w.y = pk2(f[2], f[3]);
    w.z = pk2(f[4], f[5]); w.w = pk2(f[6], f[7]);
    *(uint4*)&wT[(size_t)proj * 131072 + (size_t)n * 1024 + kc * 8] = w;
}

// ---------------------------------------------------------------------------
// Kernel 2: fused QKV projection (ROUND-10 CONFIG — proven local optimum;
// dbuf / BN-split / BK=128 / QBLK-growth / 2-phase all regressed or neutral).
// BM=64, BN=128, BK=64, 768 blocks = 3/CU, single-buffer, no cross-barrier
// register state. B via global_load_lds w=16 (pre-swizzled src, linear dest);
// A global->reg->cvt->ds_write. LDS 24 KB.
// ---------------------------------------------------------------------------
__global__ __launch_bounds__(256, 3) void k_proj(const float* __restrict__ x,
                                                 const ushort* __restrict__ wT,
                                                 ushort* __restrict__ qb,
                                                 ushort* __restrict__ kb,
                                                 ushort* __restrict__ vT) {
    const int bx = blockIdx.x;
    const int mt = bx & 255;          // 256 m-tiles of 64 rows (same-x blocks 256 apart -> same XCD)
    const int proj = bx >> 8;         // 0,1,2
    const int tid = threadIdx.x, lane = tid & 63, wid = tid >> 6;
    const int wm = wid >> 1, wn = wid & 1;
    const int m0 = mt * 64;

    __shared__ __align__(16) ushort sm[64 * 64 + 128 * 64];  // lA 8KB + lB 16KB
    ushort* lA = sm;               // [64 m][64 k] swizzled
    ushort* lB = sm + 64 * 64;     // [128 n][64 k] swizzled (data), linear dest for DMA

    const ushort* wTp = wT + (size_t)proj * 131072;
    f32x4 acc[2][4] = {};

    const int arow = tid >> 2, aq = tid & 3;   // A: row, 16-col group
    const float* xrow = x + (size_t)(m0 + arow) * 1024 + aq * 16;

    for (int kt = 0; kt < 1024; kt += 64) {
        __syncthreads();   // previous MFMA reads done
#pragma unroll
        for (int c = 0; c < 4; ++c) {
            int chunk = tid + 256 * c;
            int n = chunk >> 3, ir = (chunk & 7) * 8;
            gload16(wTp + (size_t)n * 1024 + kt + (ir ^ ((n & 7) << 3)),
                    lB + (size_t)(wid * 64 + 256 * c) * 8);
        }
        {
            const float* xs = xrow + kt;
            float4 a0 = *(const float4*)(xs);
            float4 a1 = *(const float4*)(xs + 4);
            float4 a2 = *(const float4*)(xs + 8);
            float4 a3 = *(const float4*)(xs + 12);
            uint4 w0, w1;
            w0.x = pk2(a0.x, a0.y); w0.y = pk2(a0.z, a0.w);
            w0.z = pk2(a1.x, a1.y); w0.w = pk2(a1.z, a1.w);
            w1.x = pk2(a2.x, a2.y); w1.y = pk2(a2.z, a2.w);
            w1.z = pk2(a3.x, a3.y); w1.w = pk2(a3.z, a3.w);
            const int swz = (arow & 7) << 3;
            const int ir0 = aq * 16;
            *(uint4*)&lA[arow * 64 + (ir0 ^ swz)] = w0;
            *(uint4*)&lA[arow * 64 + ((ir0 + 8) ^ swz)] = w1;
        }
        __syncthreads();   // drains vmcnt (DMA) + lgkmcnt (ds_write)

#pragma unroll
        for (int kk = 0; kk < 2; ++kk) {
            const int ir = kk * 32 + (lane >> 4) * 8;
            bf8 a[2], bv[4];
#pragma unroll
            for (int mf = 0; mf < 2; ++mf) {
                int r = wm * 32 + mf * 16 + (lane & 15);
                a[mf] = *(const bf8*)&lA[r * 64 + (ir ^ ((r & 7) << 3))];
            }
#pragma unroll
            for (int nf = 0; nf < 4; ++nf) {
                int r = wn * 64 + nf * 16 + (lane & 15);
                bv[nf] = *(const bf8*)&lB[r * 64 + (ir ^ ((r & 7) << 3))];
            }
#pragma unroll
            for (int mf = 0; mf < 2; ++mf)
#pragma unroll
                for (int nf = 0; nf < 4; ++nf)
                    acc[mf][nf] = MFMA16(a[mf], bv[nf], acc[mf][nf]);
        }
    }
    __syncthreads();   // all MFMA reads done before epilogue reuses sm

    // epilogue via LDS restage for coalesced b128 stores.
    // C/D layout (m89): col = lane&15, row = (lane>>4)*4 + i
    if (proj < 2) {
        ushort* lT = sm;  // [64 row][136]
#pragma unroll
        for (int mf = 0; mf < 2; ++mf) {
            int row = wm * 32 + mf * 16 + ((lane >> 4) << 2);
#pragma unroll
            for (int nf = 0; nf < 4; ++nf) {
                int col = wn * 64 + nf * 16 + (lane & 15);
#pragma unroll
                for (int i = 0; i < 4; ++i)
                    lT[(row + i) * 136 + col] = f2bf(acc[mf][nf][i]);
            }
        }
        __syncthreads();
        const int row = tid >> 2, seg = (tid & 3) * 32;
        ushort* dst = (proj == 0 ? qb : kb) + (size_t)(m0 + row) * 128 + seg;
        const ushort* srcr = lT + row * 136 + seg;
#pragma unroll
        for (int j = 0; j < 4; ++j)
            *(uint4*)&dst[j * 8] = *(const uint4*)&srcr[j * 8];
    } else {
        ushort* lT = sm;  // [128 h][72]
#pragma unroll
        for (int mf = 0; mf < 2; ++mf) {
            int srow = wm * 32 + mf * 16 + ((lane >> 4) << 2);
#pragma unroll
            for (int nf = 0; nf < 4; ++nf) {
                int h = wn * 64 + nf * 16 + (lane & 15);
#pragma unroll
                for (int i = 0; i < 4; ++i)
                    lT[h * 72 + srow + i] = f2bf(acc[mf][nf][i]);
            }
        }
        __syncthreads();
        const int b = m0 >> 11, s0 = m0 & 2047;
        const int h = tid >> 1, so = (tid & 1) * 32;
        ushort* dst = vT + (size_t)b * 262144 + (size_t)h * 2048 + s0 + so;
#pragma unroll
        for (int j = 0; j < 4; ++j)
            *(uint4*)&dst[j * 8] = *(const uint4*)&lT[h * 72 + so + j * 8];
    }
}

// ---------------------------------------------------------------------------
// Kernel 3a: split-K causal attention, pass 1 (ROUND-10 CONFIG, QBLK=64;
// QBLK=128 and 2-phase dbuf both regressed — bigger barrier domains and
// occupancy-halving lose). Fixed-base softmax (m == 0): P = exp(s),
// masked -> 0; row-sums via MFMA vs all-ones B. K/V staged via
// global_load_lds (pre-swizzled src, linear dest). Partials bf16.
// 1D grid 1152: b = id&7 (batch->XCD), cx = 143-(id>>3) (heavy-first).
// ---------------------------------------------------------------------------
#define NCHUNK 144

__global__ __launch_bounds__(256) void k_attn_part(const ushort* __restrict__ qb,
                                                   const ushort* __restrict__ kb,
                                                   const ushort* __restrict__ vT,
                                                   ushort* __restrict__ pacc,
                                                   float* __restrict__ pml) {
    const int id = blockIdx.x;
    const int b  = id & 7;
    const int cx = 143 - (id >> 3);      // 0..143, heavy chunks first
    int g = 0, base = 0;
#pragma unroll
    for (int gg = 0; gg < 8; ++gg) {
        int b0 = 2 * gg * (gg + 1);
        if (cx >= b0) { g = gg; base = b0; }
    }
    const int qt = 4 * g + (cx - base) / (g + 1);
    const int c  = (cx - base) % (g + 1);
    const int kt0 = 4 * c;
    const int kt1 = min(qt + 1, kt0 + 4);

    const int tid = threadIdx.x, lane = tid & 63, wid = tid >> 6;

    __shared__ __align__(16) ushort lK[64 * 128];    // [kpos][d]  swizzled data, linear DMA dest
    __shared__ __align__(16) ushort lV[128 * 64];    // [h][kpos]  swizzled data, linear DMA dest
    __shared__ __align__(16) ushort lP[4][16 * 64];  // per-wave [qrow][kpos] swizzled

    bf8 qf[4];
    {
        const ushort* qr = qb + (size_t)(b * 2048 + qt * 64 + wid * 16 + (lane & 15)) * 128;
#pragma unroll
        for (int kk = 0; kk < 4; ++kk)
            qf[kk] = *(const bf8*)&qr[kk * 32 + (lane >> 4) * 8];
    }
    bf8 onesf;
#pragma unroll
    for (int j = 0; j < 8; ++j) onesf[j] = (short)0x3F80;   // bf16 1.0

    f32x4 acc[8] = {};
    f32x4 accl = {};                                  // row sums of P
    const int r0 = wid * 16 + ((lane >> 4) << 2);     // local q row
    const int qg0 = qt * 64 + r0;

    const ushort* kbase = kb + (size_t)b * 2048 * 128;
    const ushort* vbase = vT + (size_t)b * 262144;

    for (int kt = kt0; kt < kt1; ++kt) {
        __syncthreads();   // previous-iter LDS reads done
        {
            const ushort* kbt = kbase + (size_t)kt * 64 * 128;
#pragma unroll
            for (int cc = 0; cc < 4; ++cc) {
                int chunk = tid + 256 * cc;
                int rr = chunk >> 4, ir = (chunk & 15) * 8;
                gload16(kbt + (size_t)rr * 128 + (ir ^ ((rr & 7) << 3)),
                        lK + (size_t)(wid * 64 + 256 * cc) * 8);
            }
        }
        {
            const ushort* vbt = vbase + kt * 64;
#pragma unroll
            for (int cc = 0; cc < 4; ++cc) {
                int chunk = tid + 256 * cc;
                int h = chunk >> 3, ir = (chunk & 7) * 8;
                gload16(vbt + (size_t)h * 2048 + (ir ^ ((h & 7) << 3)),
                        lV + (size_t)(wid * 64 + 256 * cc) * 8);
            }
        }
        __syncthreads();   // drains vmcnt -> tile visible to all waves

        // QK^T : S[16 q][64 k]
        f32x4 sa[4] = {};
#pragma unroll
        for (int kk = 0; kk < 4; ++kk) {
            const int ir = kk * 32 + (lane >> 4) * 8;
#pragma unroll
            for (int nf = 0; nf < 4; ++nf) {
                int rr = nf * 16 + (lane & 15);
                bf8 kf = *(const bf8*)&lK[rr * 128 + (ir ^ ((rr & 7) << 3))];
                sa[nf] = MFMA16(qf[kk], kf, sa[nf]);
            }
        }

        // P = exp(s/32), masked -> 0 (no max subtraction: |s| <= ~2)
        float p[4][4];
#pragma unroll
        for (int nf = 0; nf < 4; ++nf)
#pragma unroll
            for (int i = 0; i < 4; ++i) {
                float s = sa[nf][i] * 0.03125f;
                if (kt == qt) {
                    int kg = kt * 64 + nf * 16 + (lane & 15);
                    if (kg > qg0 + i) s = -1e30f;
                }
                p[nf][i] = __expf(s);
            }

        // P -> per-wave LDS tile (same-wave write->read)
#pragma unroll
        for (int nf = 0; nf < 4; ++nf)
#pragma unroll
            for (int i = 0; i < 4; ++i) {
                int rr = ((lane >> 4) << 2) + i, cp = nf * 16 + (lane & 15);
                lP[wid][rr * 64 + (cp ^ ((rr & 7) << 3))] = f2bf(p[nf][i]);
            }

        // PV: o[16 q][128 h] += P[16][64] . V[64][128]; l += P . ones
#pragma unroll
        for (int kk = 0; kk < 2; ++kk) {
            const int ir = kk * 32 + (lane >> 4) * 8;
            const int pr = lane & 15;
            bf8 pf = *(const bf8*)&lP[wid][pr * 64 + (ir ^ ((pr & 7) << 3))];
            accl = MFMA16(pf, onesf, accl);
#pragma unroll
            for (int nf = 0; nf < 8; ++nf) {
                int h = nf * 16 + (lane & 15);
                bf8 vf = *(const bf8*)&lV[h * 64 + (ir ^ ((h & 7) << 3))];
                acc[nf] = MFMA16(pf, vf, acc[nf]);
            }
        }
    }

    // epilogue: unnormalized partials (bf16) + row sums l (fp32)
    ushort* pa = pacc + ((size_t)(b * NCHUNK + cx) * 64) * 128;
#pragma unroll
    for (int nf = 0; nf < 8; ++nf) {
        int h = nf * 16 + (lane & 15);
#pragma unroll
        for (int i = 0; i < 4; ++i)
            pa[(size_t)(r0 + i) * 128 + h] = f2bf(acc[nf][i]);
    }
    if ((lane & 15) == 0) {
        float* pl = pml + (size_t)(b * NCHUNK + cx) * 64 + r0;
#pragma unroll
        for (int i = 0; i < 4; ++i) pl[i] = accl[i];
    }
}

// ---------------------------------------------------------------------------
// Kernel 3b: combine bf16 partials (unweighted: fixed softmax base).
// grid (8 b, 32 qt, 2 z): linear id = b + 8*qt + 256*z -> id%8 == b, the
// SAME XCD residue as k_attn_part's writers -> batch-b partials are read
// from the local XCD L2.  256 threads: row = t>>2, cols ((t&3)+4z)*16..+15
// ---------------------------------------------------------------------------
__global__ __launch_bounds__(256) void k_attn_comb(const ushort* __restrict__ pacc,
                                                   const float* __restrict__ pml,
                                                   float* __restrict__ out) {
    const int b = blockIdx.x, qt = blockIdx.y, z = blockIdx.z;
    const int tid = threadIdx.x;
    const int row = tid >> 2, cq = ((tid & 3) + 4 * z) * 16;
    const int g = qt >> 2;
    const int base = 2 * g * (g + 1) + (qt & 3) * (g + 1);
    const int nch = g + 1;   // ceil((qt+1)/4)

    float L = 0.f;
    for (int c = 0; c < nch; ++c)
        L += pml[(size_t)(b * NCHUNK + base + c) * 64 + row];
    const float inv = 1.0f / L;

    float s[16] = {};
    for (int c = 0; c < nch; ++c) {
        const ushort* pa = pacc + ((size_t)(b * NCHUNK + base + c) * 64 + row) * 128 + cq;
#pragma unroll
        for (int j = 0; j < 2; ++j) {
            uint4 t = *(const uint4*)&pa[j * 8];
            uint qw[4] = {t.x, t.y, t.z, t.w};
#pragma unroll
            for (int e = 0; e < 4; ++e) {
                s[j * 8 + 2 * e]     += bf2f((ushort)(qw[e] & 0xFFFFu));
                s[j * 8 + 2 * e + 1] += bf2f((ushort)(qw[e] >> 16));
            }
        }
    }
    float* o = out + ((size_t)(b * 2048 + qt * 64 + row)) * 128 + cq;
#pragma unroll
    for (int j = 0; j < 4; ++j) {
        f32x4 v;
#pragma unroll
        for (int e = 0; e < 4; ++e) v[e] = s[j * 4 + e] * inv;
        *(f32x4*)&o[j * 4] = v;
    }
}

// ---------------------------------------------------------------------------
extern "C" void kernel_launch(void* const* d_in, const int* in_sizes, int n_in,
                              void* d_out, int out_size, void* d_ws, size_t ws_size,
                              hipStream_t stream) {
    const float* x  = (const float*)d_in[0];
    const float* Wq = (const float*)d_in[1];
    const float* Wk = (const float*)d_in[2];
    const float* Wv = (const float*)d_in[3];
    float* out = (float*)d_out;

    char* ws = (char*)d_ws;
    ushort* qb = (ushort*)(ws);                       // bf16 [8*2048][128]  4 MB
    ushort* kb = (ushort*)(ws + (4u << 20));          // bf16 [8*2048][128]  4 MB
    ushort* vT = (ushort*)(ws + (8u << 20));          // bf16 [8][128][2048] 4 MB
    ushort* wT = (ushort*)(ws + (12u << 20));         // bf16 [3][128][1024] 768 KB
    float*  pml  = (float*)(ws + (13u << 20));        // [8][144][64] f32  0.3 MB
    ushort* pacc = (ushort*)(ws + (15u << 20));       // [8][144][64][128] bf16 18.9 MB

    k_wconvert<<<192, 256, 0, stream>>>(Wq, Wk, Wv, wT);
    k_proj<<<768, 256, 0, stream>>>(x, wT, qb, kb, vT);
    k_attn_part<<<NCHUNK * 8, 256, 0, stream>>>(qb, kb, vT, pacc, pml);
    k_attn_comb<<<dim3(8, 32, 2), 256, 0, stream>>>(pacc, pml, out);
}